// Round 1
// baseline (773.117 us; speedup 1.0000x reference)
//
#include <hip/hip_runtime.h>

#define NN 10000
#define CC 16
#define CAP 96   // max nnz/row; E[nnz]=33, sigma~5.7 -> 96 is ~11 sigma

// ---- train_mask storage-format-agnostic accessor -------------------------
// mode 0: int32 0/1, mode 1: uint8 bool, mode 2: float32 0.0/1.0
__device__ __forceinline__ bool mask_at(const void* p, int i, int mode) {
    if (mode == 0) return ((const int*)p)[i] != 0;
    if (mode == 1) return ((const unsigned char*)p)[i] != 0;
    return ((const float*)p)[i] != 0.0f;
}

// One block scans the mask buffer as 2500 u32 words and classifies storage.
__global__ void detect_mask_mode(const unsigned int* __restrict__ m, int* flag) {
    __shared__ int s_int_bad, s_flt_bad;
    if (threadIdx.x == 0) { s_int_bad = 0; s_flt_bad = 0; }
    __syncthreads();
    for (int i = threadIdx.x; i < NN / 4; i += blockDim.x) {
        unsigned w = m[i];
        if (w > 1u) s_int_bad = 1;                       // benign racy same-value store
        if (w != 0u && w != 0x3F800000u) s_flt_bad = 1;
    }
    __syncthreads();
    if (threadIdx.x == 0) {
        int mode;
        if (!s_int_bad)      mode = 0;   // all words 0/1 -> int32
        else if (!s_flt_bad) mode = 2;   // all words 0/1.0f -> float32
        else                 mode = 1;   // packed bytes -> uint8 bool
        *flag = mode;
    }
}

// ---- CSR build: one block per row, float4 scan of the 40KB row -----------
__global__ __launch_bounds__(256) void build_csr(const float* __restrict__ adj,
                                                 int* __restrict__ cols,
                                                 float* __restrict__ vals,
                                                 int* __restrict__ cnt) {
    __shared__ int lcnt;
    const int row = blockIdx.x;
    if (threadIdx.x == 0) lcnt = 0;
    __syncthreads();
    const float4* rp = (const float4*)(adj + (size_t)row * NN);
    const int base = row * CAP;
    for (int i = threadIdx.x; i < NN / 4; i += 256) {
        float4 v = rp[i];
        int j = i * 4;
        if (v.x != 0.f) { int p = atomicAdd(&lcnt, 1); if (p < CAP) { cols[base+p] = j;   vals[base+p] = v.x; } }
        if (v.y != 0.f) { int p = atomicAdd(&lcnt, 1); if (p < CAP) { cols[base+p] = j+1; vals[base+p] = v.y; } }
        if (v.z != 0.f) { int p = atomicAdd(&lcnt, 1); if (p < CAP) { cols[base+p] = j+2; vals[base+p] = v.z; } }
        if (v.w != 0.f) { int p = atomicAdd(&lcnt, 1); if (p < CAP) { cols[base+p] = j+3; vals[base+p] = v.w; } }
    }
    __syncthreads();
    if (threadIdx.x == 0) cnt[row] = (lcnt < CAP) ? lcnt : CAP;
}

// ---- Y0 = mask ? labels : 0 ---------------------------------------------
__global__ void init_y(const float* __restrict__ labels, const void* __restrict__ tmask,
                       const int* __restrict__ flag, float* __restrict__ Y) {
    int t = blockIdx.x * 256 + threadIdx.x;        // t in [0, NN*CC)
    int row = t >> 4;
    bool m = mask_at(tmask, row, *flag);
    Y[t] = m ? labels[t] : 0.0f;
}

// ---- one propagation step: Yout = mask ? labels : adj@Yin ----------------
// thread layout: c = t&15 fastest -> 16-lane groups share a row; col/val
// reads broadcast; Yin reads are 64B segments.
__global__ __launch_bounds__(256) void spmv_step(const int* __restrict__ cols,
                                                 const float* __restrict__ vals,
                                                 const int* __restrict__ cnt,
                                                 const float* __restrict__ Yin,
                                                 const float* __restrict__ labels,
                                                 const void* __restrict__ tmask,
                                                 const int* __restrict__ flag,
                                                 float* __restrict__ Yout) {
    int t = blockIdx.x * 256 + threadIdx.x;        // 625 blocks * 256 = NN*CC exactly
    int row = t >> 4, c = t & 15;
    int n = cnt[row];
    const int*   cp = cols + row * CAP;
    const float* vp = vals + row * CAP;
    float acc = 0.0f;
    for (int k = 0; k < n; k++) acc = fmaf(vp[k], Yin[cp[k] * CC + c], acc);
    bool m = mask_at(tmask, row, *flag);
    Yout[t] = m ? labels[t] : acc;
}

// ---- Gumbel straight-through hardening, one thread per row ---------------
__global__ void harden(const float* __restrict__ Yin, const float* __restrict__ gumbel,
                       const float* __restrict__ labels, const void* __restrict__ tmask,
                       const int* __restrict__ flag, float* __restrict__ Yout) {
    int row = blockIdx.x * blockDim.x + threadIdx.x;
    if (row >= NN) return;
    float l[CC];
    float mx = -1e30f;
    int am = 0;
    for (int c = 0; c < CC; c++) {
        l[c] = Yin[row * CC + c] + gumbel[row * CC + c];   // TAU = 1
        if (l[c] > mx) { mx = l[c]; am = c; }              // strict > = first-max
    }
    float e[CC], s = 0.0f;
    for (int c = 0; c < CC; c++) { e[c] = expf(l[c] - mx); s += e[c]; }
    bool m = mask_at(tmask, row, *flag);
    for (int c = 0; c < CC; c++) {
        float soft = e[c] / s;
        float hard = (c == am) ? 1.0f : 0.0f;
        float y = (hard + soft) - soft;                    // faithful ST forward
        Yout[row * CC + c] = m ? labels[row * CC + c] : y;
    }
}

// ---- dist = (adj!=0)@Y2, row-normalize, MSE vs pseudo, atomic reduce -----
__global__ __launch_bounds__(256) void mask_spmv_loss(const int* __restrict__ cols,
                                                      const int* __restrict__ cnt,
                                                      const float* __restrict__ Y2,
                                                      const float* __restrict__ pseudo,
                                                      float* __restrict__ out) {
    int t = blockIdx.x * 256 + threadIdx.x;
    int row = t >> 4;
    int n = cnt[row];
    const int* cp = cols + row * CAP;
    float acc = 0.0f;
    for (int k = 0; k < n; k++) acc += Y2[cp[k] * CC + (t & 15)];
    // row sum across the 16-lane group
    float rs = acc;
    for (int off = 8; off >= 1; off >>= 1) rs += __shfl_xor(rs, off, 16);
    float v = acc / rs;
    float d = v - pseudo[t];
    float contrib = d * d * (1.0f / (NN * CC));
    // wave64 reduce then one atomic per wave
    for (int off = 32; off >= 1; off >>= 1) contrib += __shfl_down(contrib, off, 64);
    if ((threadIdx.x & 63) == 0) atomicAdd(out, contrib);
}

extern "C" void kernel_launch(void* const* d_in, const int* in_sizes, int n_in,
                              void* d_out, int out_size, void* d_ws, size_t ws_size,
                              hipStream_t stream) {
    const float* adj    = (const float*)d_in[0];
    const float* labels = (const float*)d_in[1];
    const float* pseudo = (const float*)d_in[2];
    const float* gumbel = (const float*)d_in[3];
    const void*  tmask  = d_in[4];
    // d_in[5] = iter_step (10), d_in[6] = k_hop (1): fixed scalars in setup.

    char* ws = (char*)d_ws;
    int*   flag = (int*)(ws + 0);                          // 64 B reserved
    int*   cnt  = (int*)(ws + 64);                         // 40,000 B
    int*   cols = (int*)(ws + 40064);                      // 3,840,000 B
    float* vals = (float*)(ws + 3880064);                  // 3,840,000 B
    float* Ya   = (float*)(ws + 7720064);                  // 640,000 B
    float* Yb   = (float*)(ws + 8360064);                  // 640,000 B  (end: 9,000,064)

    float* outp = (float*)d_out;
    hipMemsetAsync(outp, 0, sizeof(float), stream);

    detect_mask_mode<<<1, 256, 0, stream>>>((const unsigned int*)tmask, flag);
    build_csr<<<NN, 256, 0, stream>>>(adj, cols, vals, cnt);
    init_y<<<(NN * CC) / 256, 256, 0, stream>>>(labels, tmask, flag, Ya);

    float* cur = Ya;
    float* nxt = Yb;
    for (int it = 0; it < 10; ++it) {
        spmv_step<<<(NN * CC) / 256, 256, 0, stream>>>(cols, vals, cnt, cur, labels, tmask, flag, nxt);
        float* tmp = cur; cur = nxt; nxt = tmp;
    }
    // cur holds the propagated Y; harden into nxt
    harden<<<(NN + 255) / 256, 256, 0, stream>>>(cur, gumbel, labels, tmask, flag, nxt);
    mask_spmv_loss<<<(NN * CC) / 256, 256, 0, stream>>>(cols, cnt, nxt, pseudo, outp);
}

// Round 2
// 636.853 us; speedup vs baseline: 1.2140x; 1.2140x over previous
//
#include <hip/hip_runtime.h>

#define NN 10000
#define CC 16
#define CAP 96    // max nnz/row; E[nnz]=33, sigma~5.7 -> ~11 sigma headroom
#define NBLK 625  // (NN*CC)/256

// ---- train_mask storage-format-agnostic accessor -------------------------
// mode 0: int32 0/1, mode 1: uint8 bool, mode 2: float32 0.0/1.0
__device__ __forceinline__ bool mask_at(const void* p, int i, int mode) {
    if (mode == 0) return ((const int*)p)[i] != 0;
    if (mode == 1) return ((const unsigned char*)p)[i] != 0;
    return ((const float*)p)[i] != 0.0f;
}

// ---- CSR build (one block per row) + mask-mode detect (extra block) ------
__global__ __launch_bounds__(256) void build_csr(const float* __restrict__ adj,
                                                 int2* __restrict__ pack,
                                                 int* __restrict__ cnt,
                                                 const unsigned int* __restrict__ mask_words,
                                                 int* __restrict__ flag) {
    if (blockIdx.x == NN) {
        // detect train_mask storage format by scanning it as u32 words
        __shared__ int s_int_bad, s_flt_bad;
        if (threadIdx.x == 0) { s_int_bad = 0; s_flt_bad = 0; }
        __syncthreads();
        for (int i = threadIdx.x; i < NN / 4; i += 256) {
            unsigned w = mask_words[i];
            if (w > 1u) s_int_bad = 1;                     // benign racy same-value store
            if (w != 0u && w != 0x3F800000u) s_flt_bad = 1;
        }
        __syncthreads();
        if (threadIdx.x == 0) {
            int mode;
            if (!s_int_bad)      mode = 0;   // int32 0/1
            else if (!s_flt_bad) mode = 2;   // float32 0.0/1.0
            else                 mode = 1;   // packed uint8 bool
            *flag = mode;
        }
        return;
    }
    __shared__ int lcnt;
    const int row = blockIdx.x;
    if (threadIdx.x == 0) lcnt = 0;
    __syncthreads();
    const float4* rp = (const float4*)(adj + (size_t)row * NN);
    int2* pb = pack + row * CAP;
    for (int i = threadIdx.x; i < NN / 4; i += 256) {
        float4 v = rp[i];
        int j = i * 4;
        if (v.x != 0.f) { int p = atomicAdd(&lcnt, 1); if (p < CAP) pb[p] = make_int2(j,     __float_as_int(v.x)); }
        if (v.y != 0.f) { int p = atomicAdd(&lcnt, 1); if (p < CAP) pb[p] = make_int2(j + 1, __float_as_int(v.y)); }
        if (v.z != 0.f) { int p = atomicAdd(&lcnt, 1); if (p < CAP) pb[p] = make_int2(j + 2, __float_as_int(v.z)); }
        if (v.w != 0.f) { int p = atomicAdd(&lcnt, 1); if (p < CAP) pb[p] = make_int2(j + 3, __float_as_int(v.w)); }
    }
    __syncthreads();
    if (threadIdx.x == 0) cnt[row] = (lcnt < CAP) ? lcnt : CAP;
}

// ---- first step fused with Y0 construction:
//      Yout = m_row ? labels_row : adj @ (m ? labels : 0) ------------------
__global__ __launch_bounds__(256) void spmv_first(const int2* __restrict__ pack,
                                                  const int* __restrict__ cnt,
                                                  const float* __restrict__ labels,
                                                  const void* __restrict__ tmask,
                                                  const int* __restrict__ flag,
                                                  float* __restrict__ Yout) {
    int t = blockIdx.x * 256 + threadIdx.x;
    int row = t >> 4, c = t & 15;
    int n = cnt[row];
    int mode = *flag;
    const int2* pp = pack + row * CAP;
    float acc = 0.0f;
    #pragma unroll 4
    for (int k = 0; k < n; k++) {
        int2 e = pp[k];
        float yv = mask_at(tmask, e.x, mode) ? labels[e.x * CC + c] : 0.0f;
        acc = fmaf(__int_as_float(e.y), yv, acc);
    }
    bool m = mask_at(tmask, row, mode);
    Yout[t] = m ? labels[t] : acc;
}

// ---- steps 2..10: Yout = m ? labels : adj @ Yin --------------------------
__global__ __launch_bounds__(256) void spmv_step(const int2* __restrict__ pack,
                                                 const int* __restrict__ cnt,
                                                 const float* __restrict__ Yin,
                                                 const float* __restrict__ labels,
                                                 const void* __restrict__ tmask,
                                                 const int* __restrict__ flag,
                                                 float* __restrict__ Yout) {
    int t = blockIdx.x * 256 + threadIdx.x;
    int row = t >> 4, c = t & 15;
    int n = cnt[row];
    const int2* pp = pack + row * CAP;
    float acc = 0.0f;
    #pragma unroll 4
    for (int k = 0; k < n; k++) {
        int2 e = pp[k];
        acc = fmaf(__int_as_float(e.y), Yin[e.x * CC + c], acc);
    }
    bool m = mask_at(tmask, row, *flag);
    Yout[t] = m ? labels[t] : acc;
}

// ---- Gumbel straight-through hardening, one thread per row ---------------
__global__ void harden(const float* __restrict__ Yin, const float* __restrict__ gumbel,
                       const float* __restrict__ labels, const void* __restrict__ tmask,
                       const int* __restrict__ flag, float* __restrict__ Yout) {
    int row = blockIdx.x * blockDim.x + threadIdx.x;
    if (row >= NN) return;
    float l[CC];
    float mx = -1e30f;
    int am = 0;
    for (int c = 0; c < CC; c++) {
        l[c] = Yin[row * CC + c] + gumbel[row * CC + c];   // TAU = 1
        if (l[c] > mx) { mx = l[c]; am = c; }              // strict > = first-max
    }
    float e[CC], s = 0.0f;
    for (int c = 0; c < CC; c++) { e[c] = expf(l[c] - mx); s += e[c]; }
    bool m = mask_at(tmask, row, *flag);
    for (int c = 0; c < CC; c++) {
        float soft = e[c] / s;
        float hard = (c == am) ? 1.0f : 0.0f;
        float y = (hard + soft) - soft;                    // faithful ST forward
        Yout[row * CC + c] = m ? labels[row * CC + c] : y;
    }
}

// ---- dist = (adj!=0)@Y2, row-normalize, MSE, per-block partial -----------
__global__ __launch_bounds__(256) void mask_spmv_loss(const int2* __restrict__ pack,
                                                      const int* __restrict__ cnt,
                                                      const float* __restrict__ Y2,
                                                      const float* __restrict__ pseudo,
                                                      float* __restrict__ partial) {
    int t = blockIdx.x * 256 + threadIdx.x;
    int row = t >> 4, c = t & 15;
    int n = cnt[row];
    const int2* pp = pack + row * CAP;
    float acc = 0.0f;
    #pragma unroll 4
    for (int k = 0; k < n; k++) acc += Y2[pp[k].x * CC + c];
    // row sum across the 16-lane group (diag guarantees rs >= ~1)
    float rs = acc;
    for (int off = 8; off >= 1; off >>= 1) rs += __shfl_xor(rs, off, 16);
    float d = acc / rs - pseudo[t];
    float contrib = d * d * (1.0f / (NN * CC));
    // wave64 reduce, then LDS across the 4 waves, ONE write per block
    for (int off = 32; off >= 1; off >>= 1) contrib += __shfl_down(contrib, off, 64);
    __shared__ float sw[4];
    if ((threadIdx.x & 63) == 0) sw[threadIdx.x >> 6] = contrib;
    __syncthreads();
    if (threadIdx.x == 0) partial[blockIdx.x] = sw[0] + sw[1] + sw[2] + sw[3];
}

// ---- sum 625 partials -> out[0] (no atomics, no memset needed) -----------
__global__ void final_reduce(const float* __restrict__ partial, float* __restrict__ out) {
    float s = 0.0f;
    for (int i = threadIdx.x; i < NBLK; i += 256) s += partial[i];
    for (int off = 32; off >= 1; off >>= 1) s += __shfl_down(s, off, 64);
    __shared__ float sw[4];
    if ((threadIdx.x & 63) == 0) sw[threadIdx.x >> 6] = s;
    __syncthreads();
    if (threadIdx.x == 0) out[0] = sw[0] + sw[1] + sw[2] + sw[3];
}

extern "C" void kernel_launch(void* const* d_in, const int* in_sizes, int n_in,
                              void* d_out, int out_size, void* d_ws, size_t ws_size,
                              hipStream_t stream) {
    const float* adj    = (const float*)d_in[0];
    const float* labels = (const float*)d_in[1];
    const float* pseudo = (const float*)d_in[2];
    const float* gumbel = (const float*)d_in[3];
    const void*  tmask  = d_in[4];
    // d_in[5] = iter_step (10), d_in[6] = k_hop (1): fixed scalars in setup.

    char* ws = (char*)d_ws;
    int*   flag    = (int*)(ws + 0);                 // 64 B reserved
    int*   cnt     = (int*)(ws + 64);                // 40,000 B
    int2*  pack    = (int2*)(ws + 40064);            // 7,680,000 B
    float* Ya      = (float*)(ws + 7720064);         // 640,000 B
    float* Yb      = (float*)(ws + 8360064);         // 640,000 B
    float* partial = (float*)(ws + 9000064);         // 2,500 B (end: 9,002,564)

    float* outp = (float*)d_out;

    build_csr<<<NN + 1, 256, 0, stream>>>(adj, pack, cnt, (const unsigned int*)tmask, flag);

    // step 1 (fused Y0 construction), then steps 2..10
    spmv_first<<<NBLK, 256, 0, stream>>>(pack, cnt, labels, tmask, flag, Ya);
    float* cur = Ya;
    float* nxt = Yb;
    for (int it = 0; it < 9; ++it) {
        spmv_step<<<NBLK, 256, 0, stream>>>(pack, cnt, cur, labels, tmask, flag, nxt);
        float* tmp = cur; cur = nxt; nxt = tmp;
    }
    harden<<<(NN + 255) / 256, 256, 0, stream>>>(cur, gumbel, labels, tmask, flag, nxt);
    mask_spmv_loss<<<NBLK, 256, 0, stream>>>(pack, cnt, nxt, pseudo, partial);
    final_reduce<<<1, 256, 0, stream>>>(partial, outp);
}